// Round 11
// baseline (376.930 us; speedup 1.0000x reference)
//
#include <hip/hip_runtime.h>
#include <hip/hip_bf16.h>

using bf16 = __hip_bfloat16;

#define DEV_INLINE __device__ __forceinline__

// Problem constants
constexpr int B_  = 4;
constexpr int LQ  = 3000;
constexpr int LK  = 750;
constexpr int NH_ = 4;
constexpr float EPSF = 1e-6f;

// LDS pitch in uint2 elements per d4-row (>=750, odd) — awg kernel.
// 751: KT2 = 24,032 B so the awg block fits 40,928 B -> 4 blocks/CU.
constexpr int PITCH = 751;

// Workspace layout (fp32 elements).
constexpr size_t WS_KV = 0;        // 6 x B*LK*64 = 1,152,000
constexpr size_t WS_XB = 1152000;  // 768,000 — now holds TRANSPOSED weights (98,304 used)
constexpr size_t WS_QP = 1920000;  // 768,000
constexpr size_t WS_AO = 2688000;  // 768,000
constexpr size_t WS_QN = 3456000;  // 768,000
constexpr size_t WS_SG = 4224000;  // 768,000

typedef _Float16 half2_t __attribute__((ext_vector_type(2)));
typedef _Float16 half4_t __attribute__((ext_vector_type(4)));
typedef float    f32x4   __attribute__((ext_vector_type(4)));

// correct gfx950 spelling (per compiler diagnostic r14): ...16x16x16f16
#define MFMA16(a, b, c) __builtin_amdgcn_mfma_f32_16x16x16f16((a), (b), (c), 0, 0, 0)

DEV_INLINE float sigmoidf(float x) { return 1.f / (1.f + __expf(-x)); }

DEV_INLINE unsigned int packh2(float a, float b) {
  half2_t h = { (_Float16)a, (_Float16)b };
  unsigned int u; __builtin_memcpy(&u, &h, 4); return u;
}
DEV_INLINE half2_t u2h(unsigned int u) {
  half2_t h; __builtin_memcpy(&h, &u, 4); return h;
}
DEV_INLINE unsigned short f2h(float f) {
  _Float16 h = (_Float16)f;
  unsigned short u; __builtin_memcpy(&u, &h, 2); return u;
}
// half4 from two 4-byte-aligned uints at p, p+2 (f16 units)
DEV_INLINE half4_t h4_from(const unsigned short* p) {
  unsigned int lo = *(const unsigned int*)p;
  unsigned int hi = *(const unsigned int*)(p + 2);
  unsigned long long v = ((unsigned long long)hi << 32) | lo;
  half4_t h; __builtin_memcpy(&h, &v, 8); return h;
}
// one v_dot2_f32_f16: acc + k.x*q.x + k.y*q.y
DEV_INLINE float dot2(unsigned int kw, half2_t qh, float acc) {
  return __builtin_amdgcn_fdot2(u2h(kw), qh, acc, false);
}

DEV_INLINE unsigned int f2sort(float f) {
  int ib = __float_as_int(f);
  return (unsigned int)(ib ^ ((ib >> 31) | 0x80000000));
}
// inverse of f2sort
DEV_INLINE float sort2f(unsigned int u) {
  const int ib = (u & 0x80000000u) ? (int)(u ^ 0x80000000u) : (int)~u;
  return __int_as_float(ib);
}

DEV_INLINE unsigned int bcastu(unsigned int v) {
  return (unsigned int)__builtin_amdgcn_readfirstlane((int)v);
}

// 4 independent descending bitonic sorts (one value/lane each) across the
// 64-lane wave — DPP/permute + VALU, ILP-4 by construction.
DEV_INLINE void sort64u_desc4(unsigned int v[4]) {
  const int lane = threadIdx.x & 63;
  #pragma unroll
  for (int k = 2; k <= 64; k <<= 1) {
    #pragma unroll
    for (int j = k >> 1; j > 0; j >>= 1) {
      const bool takeMax = ((lane & j) == 0) == ((lane & k) == 0);
      #pragma unroll
      for (int r = 0; r < 4; ++r) {
        const unsigned int o = __shfl_xor(v[r], j);
        v[r] = (takeMax == (v[r] > o)) ? v[r] : o;
      }
    }
  }
}

DEV_INLINE float row_ln(float v, float g, float b) {
  float s1 = v, s2 = v * v;
  #pragma unroll
  for (int off = 32; off > 0; off >>= 1) {
    s1 += __shfl_xor(s1, off);
    s2 += __shfl_xor(s2, off);
  }
  const float m   = s1 * (1.f / 64.f);
  const float var = s2 * (1.f / 64.f) - m * m;
  return (v - m) * rsqrtf(var + EPSF) * g + b;
}

// ---------------------------------------------------------------------------
// One-shot weight transpose into WS_XB. The GEMV kernels are weight-load-
// instruction-bound; transposed layout lets each thread stream its own row
// with dwordx4 (4x fewer load instrs). Layout (float offsets from xbT):
//   idx*4096 for idx 0..15: calWq,calWk,calWv,calWo,mWk0,mWk1,mWv0,mWv1,
//                           mWq0,mWq1,mWo0,mWo1,fc1_0,fc1_1,fc2_0,fc2_1
//   65536: W1T [256][64]   81920: W2T [64][256]
// ---------------------------------------------------------------------------
__global__ __launch_bounds__(256) void transpose_kernel(
    const float* __restrict__ calWq, const float* __restrict__ calWk,
    const float* __restrict__ calWv, const float* __restrict__ calWo,
    const float* __restrict__ mWk, const float* __restrict__ mWv,
    const float* __restrict__ mWq, const float* __restrict__ mWo,
    const float* __restrict__ fc1, const float* __restrict__ fc2,
    const float* __restrict__ W1, const float* __restrict__ W2,
    float* __restrict__ dst)
{
  const int b = blockIdx.x, t = threadIdx.x;
  if (b < 16) {
    const float* src;
    switch (b) {
      case 0:  src = calWq;        break;
      case 1:  src = calWk;        break;
      case 2:  src = calWv;        break;
      case 3:  src = calWo;        break;
      case 4:  src = mWk;          break;
      case 5:  src = mWk + 4096;   break;
      case 6:  src = mWv;          break;
      case 7:  src = mWv + 4096;   break;
      case 8:  src = mWq;          break;
      case 9:  src = mWq + 4096;   break;
      case 10: src = mWo;          break;
      case 11: src = mWo + 4096;   break;
      case 12: src = fc1;          break;
      case 13: src = fc1 + 4096;   break;
      case 14: src = fc2;          break;
      default: src = fc2 + 4096;   break;
    }
    float* d = dst + b * 4096;
    for (int i = t; i < 4096; i += 256) {
      const int r = i >> 6, c = i & 63;
      d[c * 64 + r] = src[r * 64 + c];
    }
  } else if (b < 20) {
    float* d = dst + 65536;
    const int q = b - 16;
    for (int i = t; i < 4096; i += 256) {
      const int e = q * 4096 + i;
      const int r = e >> 8, col = e & 255;
      d[col * 64 + r] = W1[r * 256 + col];
    }
  } else {
    float* d = dst + 81920;
    const int q = b - 20;
    for (int i = t; i < 4096; i += 256) {
      const int e = q * 4096 + i;
      const int r = e >> 6, cc = e & 63;
      d[cc * 256 + r] = W2[r * 64 + cc];
    }
  }
}

// generic 64-in GEMV step: acc[p] += xs[p*4+rr][c] * WT[cc][c], f4-vectorized,
// c-ascending fmaf chain (bit-identical to the scalar version).
#define GEMV64_F4(WT_row, XS, ACC)                                  \
  {                                                                 \
    const float4* wt4 = (const float4*)(WT_row);                    \
    _Pragma("unroll")                                               \
    for (int c4 = 0; c4 < 16; ++c4) {                               \
      const float4 w = wt4[c4];                                     \
      _Pragma("unroll")                                             \
      for (int p = 0; p < 4; ++p) {                                 \
        const float4 x = *(const float4*)&XS[p * 4 + rr][c4 * 4];   \
        ACC[p] = fmaf(x.x, w.x, ACC[p]);                            \
        ACC[p] = fmaf(x.y, w.y, ACC[p]);                            \
        ACC[p] = fmaf(x.z, w.z, ACC[p]);                            \
        ACC[p] = fmaf(x.w, w.w, ACC[p]);                            \
      }                                                             \
    }                                                               \
  }

// ---------------------------------------------------------------------------
// Merged projections: y<6 -> K/V of enc (188 blocks used); y==6 -> q-proj
// (750 blocks). 16 rows/block, 4 rows/thread. TRANSPOSED weights, f4 loads.
// y==2 / y==4 (AWG K slabs) are stored PACKED f16 (uint2 per 4 dims).
// ---------------------------------------------------------------------------
__global__ __launch_bounds__(256) void kvq_proj_kernel(
    const float* __restrict__ enc, const float* __restrict__ q,
    const float* __restrict__ calWqT,
    const float* __restrict__ calWkT, const float* __restrict__ calWvT,
    const float* __restrict__ mWkT, const float* __restrict__ mWvT,
    float* __restrict__ kv, float* __restrict__ qp)
{
  const int y = blockIdx.y;
  if (y < 6 && blockIdx.x >= 188) return;
  __shared__ __align__(16) float xs[16][64];
  const int t = threadIdx.x, rr = t >> 6, cc = t & 63;
  const float* WT;
  const float* src;
  float* dst;
  float scale = 1.f;
  int nrows = 3000;
  switch (y) {
    case 0: WT = calWkT;        src = enc; dst = kv;           break;
    case 1: WT = calWvT;        src = enc; dst = kv + 192000;  break;
    case 2: WT = mWkT;          src = enc; dst = kv + 384000;  break;
    case 3: WT = mWvT;          src = enc; dst = kv + 576000;  break;
    case 4: WT = mWkT + 4096;   src = enc; dst = kv + 768000;  break;
    case 5: WT = mWvT + 4096;   src = enc; dst = kv + 960000;  break;
    default: WT = calWqT; src = q; dst = qp; scale = 0.25f; nrows = 12000; break;
  }
  const bool packK = (y == 2) || (y == 4);
  const int base = blockIdx.x * 16;
  {
    const int grow = base + (t >> 4);
    float4 v = {0.f, 0.f, 0.f, 0.f};
    if (grow < nrows) v = *(const float4*)&src[(size_t)grow * 64 + (t & 15) * 4];
    ((float4*)xs)[t] = v;
  }
  __syncthreads();
  float acc[4] = {0.f, 0.f, 0.f, 0.f};
  GEMV64_F4(WT + cc * 64, xs, acc);
  #pragma unroll
  for (int p = 0; p < 4; ++p) {
    const int grow = base + p * 4 + rr;
    if (packK) {
      const float accN = __shfl_xor(acc[p], 1);   // partner dim (cc^1)
      if (!(cc & 1) && grow < nrows)
        ((unsigned int*)dst)[(size_t)grow * 32 + (cc >> 1)] = packh2(acc[p], accN);
    } else if (grow < nrows) {
      dst[(size_t)grow * 64 + cc] = acc[p] * scale;
    }
  }
}

// ---------------------------------------------------------------------------
// CROSS attention via MFMA (flash-lite, no max subtraction — logits bounded).
// grid (47, NH, B), block 256 (4 waves); wave owns 16 q-rows (block: 64).
// ---------------------------------------------------------------------------
__global__ __launch_bounds__(256) void cross_attn_kernel(
    const float* __restrict__ qp, const float* __restrict__ kp,
    const float* __restrict__ vp, float* __restrict__ ao)
{
  extern __shared__ char smem[];
  unsigned short* Kl = (unsigned short*)smem;       // [750][18]
  unsigned short* Vt = Kl + 750 * 18;               // [16][754]
  unsigned short* Pt = Vt + 16 * 754;               // [4 waves][16][18]

  const int t = threadIdx.x;
  const int h = blockIdx.y, b = blockIdx.z;
  const float* kslab = kp + (size_t)(b * LK) * 64 + h * 16;
  const float* vslab = vp + (size_t)(b * LK) * 64 + h * 16;

  // stage K (row-major f16, pitch 18) and V transposed ([d][key])
  for (int k = t; k < LK; k += 256) {
    const float4* ks = (const float4*)(kslab + (size_t)k * 64);
    const float4* vs = (const float4*)(vslab + (size_t)k * 64);
    unsigned int* kr = (unsigned int*)(Kl + k * 18);
    #pragma unroll
    for (int q4 = 0; q4 < 4; ++q4) {
      float4 a = ks[q4], v = vs[q4];
      kr[q4 * 2]     = packh2(a.x, a.y);
      kr[q4 * 2 + 1] = packh2(a.z, a.w);
      Vt[(q4 * 4 + 0) * 754 + k] = f2h(v.x);
      Vt[(q4 * 4 + 1) * 754 + k] = f2h(v.y);
      Vt[(q4 * 4 + 2) * 754 + k] = f2h(v.z);
      Vt[(q4 * 4 + 3) * 754 + k] = f2h(v.w);
    }
  }
  // zero V pad keys 750..751 (P is masked there, but 0*NaN would poison O)
  if (t < 32) Vt[(t & 15) * 754 + 750 + (t >> 4)] = 0;
  __syncthreads();

  const int wave = t >> 6, lane = t & 63;
  const int col = lane & 15, quad = lane >> 4;
  const int qbase = blockIdx.x * 64 + wave * 16;
  unsigned short* Pt_w = Pt + wave * 288;   // [16][18]

  // Q A-fragment: A[m=col][k=quad*4+j], constant across tiles
  int qrow = qbase + col; if (qrow >= LQ) qrow = LQ - 1;
  const float* qptr = qp + ((size_t)(b * LQ + qrow)) * 64 + h * 16 + quad * 4;
  half4_t aQ;
  {
    unsigned long long v = ((unsigned long long)packh2(qptr[2], qptr[3]) << 32)
                         | packh2(qptr[0], qptr[1]);
    __builtin_memcpy(&aQ, &v, 8);
  }

  f32x4 O = {0.f, 0.f, 0.f, 0.f};
  float Zp[4] = {0.f, 0.f, 0.f, 0.f};
  const f32x4 zeroC = {0.f, 0.f, 0.f, 0.f};

  for (int tile = 0; tile < 47; ++tile) {
    const int key = tile * 16 + col;
    // B-fragment K^T: B[k=quad*4+j][n=col] = K[key=n][k]
    const half4_t bK = h4_from(Kl + key * 18 + quad * 4);
    f32x4 S = MFMA16(aQ, bK, zeroC);
    // exp + mask (C layout: col=lane&15 -> key, row=quad*4+r)
    const bool valid = key < LK;
    float e0 = valid ? __expf(S[0]) : 0.f;
    float e1 = valid ? __expf(S[1]) : 0.f;
    float e2 = valid ? __expf(S[2]) : 0.f;
    float e3 = valid ? __expf(S[3]) : 0.f;
    Zp[0] += e0; Zp[1] += e1; Zp[2] += e2; Zp[3] += e3;
    // C->A transpose through wave-private LDS tile (barrier-free)
    Pt_w[(quad * 4 + 0) * 18 + col] = f2h(e0);
    Pt_w[(quad * 4 + 1) * 18 + col] = f2h(e1);
    Pt_w[(quad * 4 + 2) * 18 + col] = f2h(e2);
    Pt_w[(quad * 4 + 3) * 18 + col] = f2h(e3);
    const half4_t aP = h4_from(Pt_w + col * 18 + quad * 4);
    // B-fragment V: B[k=quad*4+j][n=col] = V[key=tile*16+quad*4+j][d=col]
    const half4_t bV = h4_from(Vt + col * 754 + tile * 16 + quad * 4);
    O = MFMA16(aP, bV, O);
  }

  // reduce Z across the 16-lane col group (rows quad*4+r live there)
  #pragma unroll
  for (int r = 0; r < 4; ++r) {
    float z = Zp[r];
    z += __shfl_xor(z, 1);
    z += __shfl_xor(z, 2);
    z += __shfl_xor(z, 4);
    z += __shfl_xor(z, 8);
    Zp[r] = z;
  }

  #pragma unroll
  for (int r = 0; r < 4; ++r) {
    const int orow = qbase + quad * 4 + r;
    if (orow < LQ)
      ao[((size_t)(b * LQ + orow)) * 64 + h * 16 + col] = O[r] / Zp[r];
  }
}

// ---------------------------------------------------------------------------
// AWG attention v5 (R8 verbatim — the proven 59.3 µs variant).
// grid (94, NH, B), block 512 (8 waves, 4 q-rows/wave). 4 blocks/CU.
// ---------------------------------------------------------------------------
__global__ __launch_bounds__(512) void awg_attn_kernel(
    const float* __restrict__ qp, const unsigned int* __restrict__ kp,
    const float* __restrict__ vp, float* __restrict__ ao)
{
  extern __shared__ char smem[];
  uint2*          KT2   = (uint2*)smem;                                      // [4][PITCH] = 24,032 B
  unsigned int*   candV = (unsigned int*)(smem + 4 * PITCH * 8);             // [8][4][64] = 8,192
  unsigned short* candK = (unsigned short*)(smem + 4 * PITCH * 8 + 8192);    // [8][4][64] = 4,096
  float*          selW  = (float*)(smem + 4 * PITCH * 8 + 8192 + 4096);      // [8][4][24] = 3,072
  unsigned short* selK  = (unsigned short*)(smem + 4 * PITCH * 8 + 8192 + 4096 + 3072); // 1,536

  const int t = threadIdx.x;
  const int h = blockIdx.y, b = blockIdx.z;
  const unsigned int* kslab = kp + ((size_t)(b * LK)) * 32 + h * 8;

  for (int k = t; k < LK; k += 512) {
    const uint2* ks = (const uint2*)(kslab + (size_t)k * 32);
    #pragma unroll
    for (int d4 = 0; d4 < 4; ++d4) KT2[d4 * PITCH + k] = ks[d4];
  }
  __syncthreads();

  const int wave = t >> 6, lane = t & 63;
  const unsigned long long below = (1ull << lane) - 1ull;
  unsigned int*   cV = candV + wave * 256;
  unsigned short* cK = candK + wave * 256;
  float*          sW = selW + wave * 96;
  unsigned short* sK = selK + wave * 96;

  // pad select arrays (wave-private; unwritten tail -> exp()==0 in gather)
  sW[lane] = -3.0e38f; sK[lane] = 0;
  if (lane < 32) { sW[64 + lane] = -3.0e38f; sK[64 + lane] = 0; }
  // zero candidate values (pads sort to the tail and never pass >= T)
  #pragma unroll
  for (int r = 0; r < 4; ++r) cV[r * 64 + lane] = 0u;

  const int r0 = blockIdx.x * 32 + wave * 4;
  int r0r = r0; if (r0r > LQ - 4) r0r = LQ - 4;   // clamp reads; stores guarded
  const float* qrow = qp + ((size_t)(b * LQ + r0r)) * 64 + h * 16;
  unsigned int qw[4][8];   // wave-uniform packed f16 q -> SGPRs
  #pragma unroll
  for (int r = 0; r < 4; ++r) {
    #pragma unroll
    for (int i = 0; i < 8; ++i)
      qw[r][i] = bcastu(packh2(qrow[r * 64 + 2 * i], qrow[r * 64 + 2 * i + 1]));
  }

  float lg[4][12];
  #pragma unroll
  for (int tt = 0; tt < 12; ++tt) {
    const int k = lane + (tt << 6);
    if (tt < 11 || k < LK) {
      float a0 = 0.f, a1 = 0.f, a2 = 0.f, a3 = 0.f;
      #pragma unroll
      for (int d4 = 0; d4 < 4; ++d4) {
        const uint2 w = KT2[d4 * PITCH + k];
        a0 = dot2(w.x, u2h(qw[0][2 * d4]), a0); a0 = dot2(w.y, u2h(qw[0][2 * d4 + 1]), a0);
        a1 = dot2(w.x, u2h(qw[1][2 * d4]), a1); a1 = dot2(w.y, u2h(qw[1][2 * d4 + 1]), a1);
        a2 = dot2(w.x, u2h(qw[2][2 * d4]), a2); a2 = dot2(w.y, u2h(qw[2][2 * d4 + 1]), a2);
        a3 = dot2(w.x, u2h(qw[3][2 * d4]), a3); a3 = dot2(w.y, u2h(qw[3][2 * d4 + 1]), a3);
      }
      lg[0][tt] = a0; lg[1][tt] = a1; lg[2][tt] = a2; lg[3][tt] = a3;
    } else {
      lg[0][tt] = -3.0e38f; lg[1][tt] = -3.0e38f;
      lg[2][tt] = -3.0e38f; lg[3][tt] = -3.0e38f;
    }
  }

  // per-lane heads (max of this lane's 12 keys) per row
  unsigned int hs[4];
  #pragma unroll
  for (int r = 0; r < 4; ++r) {
    float m = lg[r][0];
    #pragma unroll
    for (int tt = 1; tt < 12; ++tt) m = fmaxf(m, lg[r][tt]);
    hs[r] = f2sort(m);
  }

  // stage 1: sort heads descending -> L = exact 16th largest head
  sort64u_desc4(hs);
  unsigned int L[4];
  #pragma unroll
  for (int r = 0; r < 4; ++r) L[r] = __shfl(hs[r], 15);

  // stage 2: compact candidates (value u32 + key u16)
  int cb[4] = {0, 0, 0, 0};
  #pragma unroll
  for (int tt = 0; tt < 12; ++tt) {
    const int k = lane + (tt << 6);
    #pragma unroll
    for (int r = 0; r < 4; ++r) {
      const unsigned int s = f2sort(lg[r][tt]);
      const bool p = s >= L[r];
      const unsigned long long m = __ballot(p);
      if (p) {
        const int pos = cb[r] + (int)__popcll(m & below);
        if (pos < 64) { cV[r * 64 + pos] = s; cK[r * 64 + pos] = (unsigned short)k; }
      }
      cb[r] += (int)__popcll(m);
    }
  }

  // stage 3: sort candidate VALUES descending -> T@lane15, M@lane0
  unsigned int su[4], so[4];
  #pragma unroll
  for (int r = 0; r < 4; ++r) { su[r] = cV[r * 64 + lane]; so[r] = su[r]; }
  sort64u_desc4(so);
  unsigned int T[4]; float Mv[4];
  #pragma unroll
  for (int r = 0; r < 4; ++r) {
    T[r]  = __shfl(so[r], 15);
    Mv[r] = sort2f(__shfl(so[r], 0));
  }

  // kept set (value >= T; pads su==0 < T always); compact write, cap 24
  #pragma unroll
  for (int r = 0; r < 4; ++r) {
    const bool w = su[r] >= T[r];
    const unsigned long long mw = __ballot(w);
    if (w) {
      const int pos = (int)__popcll(mw & below);
      if (pos < 24) { sW[r * 24 + pos] = sort2f(su[r]); sK[r * 24 + pos] = cK[r * 64 + lane]; }
    }
  }

  // gather: 16 lanes per row (dd = dim), fixed 24 slots, fully unrolled
  const int dd = lane & 15;
  const int rsel = lane >> 4;
  const float ref = (rsel == 0) ? Mv[0] : (rsel == 1) ? Mv[1] : (rsel == 2) ? Mv[2] : Mv[3];
  const float* cwr = sW + rsel * 24;
  const unsigned short* cir = sK + rsel * 24;
  const float* vbase = vp + (size_t)(b * LK) * 64 + h * 16 + dd;
  float acc = 0.f, Z = 0.f;
  #pragma unroll
  for (int j = 0; j < 24; ++j) {
    const float e = __expf(cwr[j] - ref);
    Z += e;
    acc = fmaf(e, vbase[(size_t)cir[j] * 64], acc);
  }
  if (r0 + rsel < LQ)
    ao[((size_t)(b * LQ + r0 + rsel)) * 64 + h * 16 + dd] = acc / Z;
}

// ---------------------------------------------------------------------------
// FUSED cross-FFN + MGAN pre (layer 0). 16 rows/block, grid 750, 4
// rows/thread. TRANSPOSED weights, dwordx4 loads (4x fewer load instrs).
// c-ascending fmaf chains -> bit-identical to R8.
// ---------------------------------------------------------------------------
__global__ __launch_bounds__(256) void ffn_pre_kernel(
    const float* __restrict__ ao, const float* __restrict__ qres,
    const float* __restrict__ WoT,
    const float* __restrict__ g1, const float* __restrict__ b1n,
    const float* __restrict__ W1T, const float* __restrict__ bb1,
    const float* __restrict__ W2T, const float* __restrict__ bb2,
    const float* __restrict__ g2, const float* __restrict__ b2n,
    const float* __restrict__ lng, const float* __restrict__ lnb,
    const float* __restrict__ fc1T, const float* __restrict__ fc1b,
    const float* __restrict__ fc2T, const float* __restrict__ fc2b,
    const float* __restrict__ WqT,
    float* __restrict__ qn, float* __restrict__ sg, float* __restrict__ qp)
{
  __shared__ __align__(16) float xs[16][64];
  __shared__ __align__(16) float hsm[16][256];
  const int t = threadIdx.x, rr = t >> 6, cc = t & 63;
  const size_t base = (size_t)blockIdx.x * 16;
  ((float4*)xs)[t] = *(const float4*)&ao[base * 64 + t * 4];
  __syncthreads();
  float acc[4] = {0.f, 0.f, 0.f, 0.f};
  GEMV64_F4(WoT + cc * 64, xs, acc);
  #pragma unroll
  for (int p = 0; p < 4; ++p) acc[p] += qres[(base + p * 4 + rr) * 64 + cc];
  __syncthreads();
  float x1[4];
  #pragma unroll
  for (int p = 0; p < 4; ++p) {
    x1[p] = row_ln(acc[p], g1[cc], b1n[cc]);
    xs[p * 4 + rr][cc] = x1[p];
  }
  __syncthreads();
  {
    float hv[16];
    #pragma unroll
    for (int r = 0; r < 16; ++r) hv[r] = 0.f;
    const float4* w1t4 = (const float4*)(W1T + t * 64);
    #pragma unroll 4
    for (int c4 = 0; c4 < 16; ++c4) {
      const float4 w = w1t4[c4];
      #pragma unroll
      for (int r = 0; r < 16; ++r) {
        const float4 x = *(const float4*)&xs[r][c4 * 4];
        hv[r] = fmaf(x.x, w.x, hv[r]);
        hv[r] = fmaf(x.y, w.y, hv[r]);
        hv[r] = fmaf(x.z, w.z, hv[r]);
        hv[r] = fmaf(x.w, w.w, hv[r]);
      }
    }
    const float bb = bb1[t];
    #pragma unroll
    for (int r = 0; r < 16; ++r) hsm[r][t] = fmaxf(hv[r] + bb, 0.f);
  }
  __syncthreads();
  float acc2[4];
  #pragma unroll
  for (int p = 0; p < 4; ++p) acc2[p] = bb2[cc];
  {
    const float4* w2t4 = (const float4*)(W2T + cc * 256);
    #pragma unroll 8
    for (int c4 = 0; c4 < 64; ++c4) {
      const float4 w = w2t4[c4];
      #pragma unroll
      for (int p = 0; p < 4; ++p) {
        const float4 x = *(const float4*)&hsm[p * 4 + rr][c4 * 4];
        acc2[p] = fmaf(x.x, w.x, acc2[p]);
        acc2[p] = fmaf(x.y, w.y, acc2[p]);
        acc2[p] = fmaf(x.z, w.z, acc2[p]);
        acc2[p] = fmaf(x.w, w.w, acc2[p]);
      }
    }
  }
  // x = LN(ffn + x1); qn = LN(x) — xs reuse safe (post-W1 barrier above)
  float qv[4];
  #pragma unroll
  for (int p = 0; p < 4; ++p) {
    const float xv = row_ln(acc2[p] + x1[p], g2[cc], b2n[cc]);
    qv[p] = row_ln(xv, lng[cc], lnb[cc]);
    qn[(base + p * 4 + rr) * 64 + cc] = qv[p];
  }
  __syncthreads();
  #pragma unroll
  for (int p = 0; p < 4; ++p) xs[p * 4 + rr][cc] = qv[p];
  __syncthreads();
  float d1[4], d2[4];
  #pragma unroll
  for (int p = 0; p < 4; ++p) { d1[p] = fc1b[cc]; d2[p] = fc2b[cc]; }
  {
    const float4* f1t4 = (const float4*)(fc1T + cc * 64);
    const float4* f2t4 = (const float4*)(fc2T + cc * 64);
    #pragma unroll 4
    for (int c4 = 0; c4 < 16; ++c4) {
      const float4 w1 = f1t4[c4];
      const float4 w2 = f2t4[c4];
      #pragma unroll
      for (int p = 0; p < 4; ++p) {
        const float4 x = *(const float4*)&xs[p * 4 + rr][c4 * 4];
        d1[p] = fmaf(x.x, w1.x, d1[p]); d2[p] = fmaf(x.x, w2.x, d2[p]);
        d1[p] = fmaf(x.y, w1.y, d1[p]); d2[p] = fmaf(x.y, w2.y, d2[p]);
        d1[p] = fmaf(x.z, w1.z, d1[p]); d2[p] = fmaf(x.z, w2.z, d2[p]);
        d1[p] = fmaf(x.w, w1.w, d1[p]); d2[p] = fmaf(x.w, w2.w, d2[p]);
      }
    }
  }
  float sv[4];
  #pragma unroll
  for (int p = 0; p < 4; ++p) {
    sv[p] = sigmoidf(d1[p]) * d2[p];
    sg[(base + p * 4 + rr) * 64 + cc] = sv[p];
  }
  __syncthreads();
  #pragma unroll
  for (int p = 0; p < 4; ++p) xs[p * 4 + rr][cc] = sv[p];
  __syncthreads();
  float aq[4] = {0.f, 0.f, 0.f, 0.f};
  GEMV64_F4(WqT + cc * 64, xs, aq);
  #pragma unroll
  for (int p = 0; p < 4; ++p)
    qp[(base + p * 4 + rr) * 64 + cc] = aq[p] * 0.25f;
}

// ---------------------------------------------------------------------------
// Fused awg_out(layer i) + mgan_pre(layer i+1): x never touches HBM.
// 16 rows/block, grid 750, 4 rows/thread, TRANSPOSED weights (f4 loads).
// ---------------------------------------------------------------------------
__global__ __launch_bounds__(256) void out_pre_kernel(
    const float* __restrict__ ao, const float* __restrict__ sg,
    const float* __restrict__ qn, const float* __restrict__ WoT,
    const float* __restrict__ g_, const float* __restrict__ b_,
    const float* __restrict__ lng, const float* __restrict__ lnb,
    const float* __restrict__ W1T, const float* __restrict__ bb1,
    const float* __restrict__ W2T, const float* __restrict__ bb2,
    const float* __restrict__ WqT,
    float* __restrict__ qn_out, float* __restrict__ sg_out,
    float* __restrict__ qp_out)
{
  __shared__ __align__(16) float xs[16][64];
  const int t = threadIdx.x, rr = t >> 6, cc = t & 63;
  const size_t base = (size_t)blockIdx.x * 16;
  ((float4*)xs)[t] = *(const float4*)&ao[base * 64 + t * 4];
  __syncthreads();
  float accp[4] = {0.f, 0.f, 0.f, 0.f}, sgv[4];
  GEMV64_F4(WoT + cc * 64, xs, accp);
  #pragma unroll
  for (int p = 0; p < 4; ++p) {
    sgv[p] = sg[(base + p * 4 + rr) * 64 + cc];
    accp[p] += sgv[p];
  }
  __syncthreads();
  float qv[4];
  #pragma unroll
  for (int p = 0; p < 4; ++p) {
    const size_t idx = (base + p * 4 + rr) * 64 + cc;
    const float awg = row_ln(accp[p], g_[cc], b_[cc]);
    const float xv = qn[idx] + sgv[p] * sigmoidf(awg);
    qv[p] = row_ln(xv, lng[cc], lnb[cc]);
    qn_out[idx] = qv[p];
    xs[p * 4 + rr][cc] = qv[p];
  }
  __syncthreads();
  float d1[4], d2[4];
  #pragma unroll
  for (int p = 0; p < 4; ++p) { d1[p] = bb1[cc]; d2[p] = bb2[cc]; }
  {
    const float4* f1t4 = (const float4*)(W1T + cc * 64);
    const float4* f2t4 = (const float4*)(W2T + cc * 64);
    #pragma unroll 4
    for (int c4 = 0; c4 < 16; ++c4) {
      const float4 w1 = f1t4[c4];
      const float4 w2 = f2t4[c4];
      #pragma unroll
      for (int p = 0; p < 4; ++p) {
        const float4 x = *(const float4*)&xs[p * 4 + rr][c4 * 4];
        d1[p] = fmaf(x.x, w1.x, d1[p]); d2[p] = fmaf(x.x, w2.x, d2[p]);
        d1[p] = fmaf(x.y, w1.y, d1[p]); d2[p] = fmaf(x.y, w2.y, d2[p]);
        d1[p] = fmaf(x.z, w1.z, d1[p]); d2[p] = fmaf(x.z, w2.z, d2[p]);
        d1[p] = fmaf(x.w, w1.w, d1[p]); d2[p] = fmaf(x.w, w2.w, d2[p]);
      }
    }
  }
  __syncthreads();
  float sv[4];
  #pragma unroll
  for (int p = 0; p < 4; ++p) {
    sv[p] = sigmoidf(d1[p]) * d2[p];
    sg_out[(base + p * 4 + rr) * 64 + cc] = sv[p];
    xs[p * 4 + rr][cc] = sv[p];
  }
  __syncthreads();
  float aq[4] = {0.f, 0.f, 0.f, 0.f};
  GEMV64_F4(WqT + cc * 64, xs, aq);
  #pragma unroll
  for (int p = 0; p < 4; ++p)
    qp_out[(base + p * 4 + rr) * 64 + cc] = aq[p] * 0.25f;
}

// ---------------------------------------------------------------------------
// Fused awg_out(layer 1) + head: out = sigmoid(x2 @ fcW + fcb).
// 16 rows/block, grid 750, 4 rows/thread, TRANSPOSED Wo (f4 loads).
// ---------------------------------------------------------------------------
__global__ __launch_bounds__(256) void out_final_kernel(
    const float* __restrict__ ao, const float* __restrict__ sg,
    const float* __restrict__ qn, const float* __restrict__ WoT,
    const float* __restrict__ g_, const float* __restrict__ b_,
    const float* __restrict__ fw, const float* __restrict__ fb,
    float* __restrict__ out)
{
  __shared__ __align__(16) float xs[16][64];
  const int t = threadIdx.x, rr = t >> 6, cc = t & 63;
  const size_t base = (size_t)blockIdx.x * 16;
  ((float4*)xs)[t] = *(const float4*)&ao[base * 64 + t * 4];
  __syncthreads();
  float accp[4] = {0.f, 0.f, 0.f, 0.f};
  GEMV64_F4(WoT + cc * 64, xs, accp);
  #pragma unroll
  for (int p = 0; p < 4; ++p) {
    const size_t idx = (base + p * 4 + rr) * 64 + cc;
    const float sgv = sg[idx];
    const float a = accp[p] + sgv;
    const float awg = row_ln(a, g_[cc], b_[cc]);
    const float xv = qn[idx] + sgv * sigmoidf(awg);
    float v = xv * fw[cc];
    #pragma unroll
    for (int off = 32; off > 0; off >>= 1) v += __shfl_xor(v, off);
    if (cc == 0) out[base + p * 4 + rr] = sigmoidf(v + fb[0]);
  }
}

// ---------------------------------------------------------------------------
extern "C" void kernel_launch(void* const* d_in, const int* in_sizes, int n_in,
                              void* d_out, int out_size, void* d_ws, size_t ws_size,
                              hipStream_t stream) {
  (void)in_sizes; (void)n_in; (void)out_size; (void)ws_size;

  const float* q     = (const float*)d_in[0];
  const float* enc   = (const float*)d_in[1];
  const float* calWq = (const float*)d_in[2];
  const float* calWk = (const float*)d_in[3];
  const float* calWv = (const float*)d_in[4];
  const float* calWo = (const float*)d_in[5];
  const float* ln1g  = (const float*)d_in[6];
  const float* ln1b  = (const float*)d_in[7];
  const float* W1    = (const float*)d_in[8];
  const float* b1v   = (const float*)d_in[9];
  const float* W2    = (const float*)d_in[10];
  const float* b2v   = (const float*)d_in[11];
  const float* ln2g  = (const float*)d_in[12];
  const float* ln2b  = (const float*)d_in[13];
  const float* mlng  = (const float*)d_in[14];
  const float* mlnb  = (const float*)d_in[15];
  const float* mfc1W = (const float*)d_in[16];
  const float* mfc1b = (const float*)d_in[17];
  const float* mfc2W = (const float*)d_in[18];
  const float* mfc2b = (const float*)d_in[19];
  const float* mWq   = (const float*)d_in[20];
  const float* mWk   = (const float*)d_in[21];
  const float* mWv   = (const float*)d_in[22];
  const float* mWo   = (const float*)d_in[23];
  const float* malng = (const float*)d_in[24];
  const float* malnb = (const float*)d_in[25];
  const float* fcW   = (const float*)d_in[26];
  const float* fcb   = (const float*)d_in[27];
  float* out = (float*)d_out;

  float* ws  = (float*)d_ws;
  float* kv  = ws + WS_KV;
  float* qp  = ws + WS_QP;
  float* aob = ws + WS_AO;
  float* qnb = ws + WS_QN;
  float* sgb = ws + WS_SG;
  float* xbT = ws + WS_XB;   // transposed weights

  // transposed-weight sub-pointers (layout: see transpose_kernel)
  const float* calWqT = xbT;
  const float* calWkT = xbT + 4096;
  const float* calWvT = xbT + 8192;
  const float* calWoT = xbT + 12288;
  const float* mWkT   = xbT + 16384;   // +4096 for layer 1
  const float* mWvT   = xbT + 24576;   // +4096 for layer 1
  const float* mWqT   = xbT + 32768;   // +4096 for layer 1
  const float* mWoT   = xbT + 40960;   // +4096 for layer 1
  const float* fc1T   = xbT + 49152;   // +4096 for layer 1
  const float* fc2T   = xbT + 57344;   // +4096 for layer 1
  const float* W1T    = xbT + 65536;
  const float* W2T    = xbT + 81920;

  const size_t crossLds = (750 * 18 + 16 * 754 + 4 * 288) * 2;        // 53,432 B
  const size_t awgLds   = 4 * PITCH * 8 + 8192 + 4096 + 3072 + 1536;  // 40,928 B

  // 0) one-shot weight transpose (enables dwordx4 weight streaming)
  transpose_kernel<<<24, 256, 0, stream>>>(calWq, calWk, calWv, calWo,
                                           mWk, mWv, mWq, mWo,
                                           mfc1W, mfc2W, W1, W2, xbT);

  // 1) all K/V projections + cross q-projection in one dispatch
  //    (awg K slabs y==2/y==4 stored packed f16)
  kvq_proj_kernel<<<dim3(750, 7), 256, 0, stream>>>(enc, q, calWqT, calWkT,
                                                    calWvT, mWkT, mWvT, kv, qp);

  // 2) cross attention (MFMA flash-lite) + fused FFN+MGAN-pre epilogue
  cross_attn_kernel<<<dim3(47, NH_, B_), 256, crossLds, stream>>>(qp, kv, kv + 192000, aob);
  ffn_pre_kernel<<<750, 256, 0, stream>>>(aob, q, calWoT, ln1g, ln1b,
                                          W1T, b1v, W2T, b2v, ln2g, ln2b,
                                          mlng, mlnb, fc1T, mfc1b,
                                          fc2T, mfc2b, mWqT, qnb, sgb, qp);

  // 3) MGAN layer 0 attention + fused out/pre
  awg_attn_kernel<<<dim3(94, NH_, B_), 512, awgLds, stream>>>(
      qp, (const unsigned int*)(kv + 2 * 192000), kv + 3 * 192000, aob);
  out_pre_kernel<<<750, 256, 0, stream>>>(aob, sgb, qnb, mWoT, malng, malnb,
                                          mlng + 64, mlnb + 64,
                                          fc1T + 4096, mfc1b + 64,
                                          fc2T + 4096, mfc2b + 64,
                                          mWqT + 4096, qnb, sgb, qp);

  // 4) MGAN layer 1 + head
  awg_attn_kernel<<<dim3(94, NH_, B_), 512, awgLds, stream>>>(
      qp, (const unsigned int*)(kv + 4 * 192000), kv + 5 * 192000, aob);
  out_final_kernel<<<750, 256, 0, stream>>>(aob, sgb, qnb, mWoT + 4096,
                                            malng + 64, malnb + 64, fcW, fcb, out);
}

// Round 12
// 313.031 us; speedup vs baseline: 1.2041x; 1.2041x over previous
//
#include <hip/hip_runtime.h>
#include <hip/hip_bf16.h>

using bf16 = __hip_bfloat16;

#define DEV_INLINE __device__ __forceinline__

// Problem constants
constexpr int B_  = 4;
constexpr int LQ  = 3000;
constexpr int LK  = 750;
constexpr int NH_ = 4;
constexpr float EPSF = 1e-6f;

// LDS pitch in uint2 elements per d4-row (>=750, odd) — awg kernel.
// 751: KT2 = 24,032 B so the awg block fits 40,928 B -> 4 blocks/CU.
constexpr int PITCH = 751;

// Workspace layout (fp32 elements).
constexpr size_t WS_KV = 0;        // 6 x B*LK*64 = 1,152,000
constexpr size_t WS_XB = 1152000;  // B*LQ*64 = 768,000 (unused)
constexpr size_t WS_QP = 1920000;  // 768,000
constexpr size_t WS_AO = 2688000;  // 768,000
constexpr size_t WS_QN = 3456000;  // 768,000
constexpr size_t WS_SG = 4224000;  // 768,000

typedef _Float16 half2_t __attribute__((ext_vector_type(2)));
typedef _Float16 half4_t __attribute__((ext_vector_type(4)));
typedef float    f32x4   __attribute__((ext_vector_type(4)));

// correct gfx950 spelling (per compiler diagnostic r14): ...16x16x16f16
#define MFMA16(a, b, c) __builtin_amdgcn_mfma_f32_16x16x16f16((a), (b), (c), 0, 0, 0)

DEV_INLINE float sigmoidf(float x) { return 1.f / (1.f + __expf(-x)); }

DEV_INLINE unsigned int packh2(float a, float b) {
  half2_t h = { (_Float16)a, (_Float16)b };
  unsigned int u; __builtin_memcpy(&u, &h, 4); return u;
}
DEV_INLINE half2_t u2h(unsigned int u) {
  half2_t h; __builtin_memcpy(&h, &u, 4); return h;
}
DEV_INLINE unsigned short f2h(float f) {
  _Float16 h = (_Float16)f;
  unsigned short u; __builtin_memcpy(&u, &h, 2); return u;
}
// half4 from two 4-byte-aligned uints at p, p+2 (f16 units)
DEV_INLINE half4_t h4_from(const unsigned short* p) {
  unsigned int lo = *(const unsigned int*)p;
  unsigned int hi = *(const unsigned int*)(p + 2);
  unsigned long long v = ((unsigned long long)hi << 32) | lo;
  half4_t h; __builtin_memcpy(&h, &v, 8); return h;
}
// one v_dot2_f32_f16: acc + k.x*q.x + k.y*q.y
DEV_INLINE float dot2(unsigned int kw, half2_t qh, float acc) {
  return __builtin_amdgcn_fdot2(u2h(kw), qh, acc, false);
}

DEV_INLINE unsigned int f2sort(float f) {
  int ib = __float_as_int(f);
  return (unsigned int)(ib ^ ((ib >> 31) | 0x80000000));
}
// inverse of f2sort
DEV_INLINE float sort2f(unsigned int u) {
  const int ib = (u & 0x80000000u) ? (int)(u ^ 0x80000000u) : (int)~u;
  return __int_as_float(ib);
}

DEV_INLINE unsigned int bcastu(unsigned int v) {
  return (unsigned int)__builtin_amdgcn_readfirstlane((int)v);
}

// 4 independent descending bitonic sorts (one value/lane each) across the
// 64-lane wave — DPP/permute + VALU, ILP-4 by construction.
DEV_INLINE void sort64u_desc4(unsigned int v[4]) {
  const int lane = threadIdx.x & 63;
  #pragma unroll
  for (int k = 2; k <= 64; k <<= 1) {
    #pragma unroll
    for (int j = k >> 1; j > 0; j >>= 1) {
      const bool takeMax = ((lane & j) == 0) == ((lane & k) == 0);
      #pragma unroll
      for (int r = 0; r < 4; ++r) {
        const unsigned int o = __shfl_xor(v[r], j);
        v[r] = (takeMax == (v[r] > o)) ? v[r] : o;
      }
    }
  }
}

DEV_INLINE float row_ln(float v, float g, float b) {
  float s1 = v, s2 = v * v;
  #pragma unroll
  for (int off = 32; off > 0; off >>= 1) {
    s1 += __shfl_xor(s1, off);
    s2 += __shfl_xor(s2, off);
  }
  const float m   = s1 * (1.f / 64.f);
  const float var = s2 * (1.f / 64.f) - m * m;
  return (v - m) * rsqrtf(var + EPSF) * g + b;
}

// ---------------------------------------------------------------------------
// Merged projections: y<6 -> K/V of enc (188 blocks used); y==6 -> q-proj
// (750 blocks). 16 rows/block, 4 rows/thread. Weights read DIRECT from L2
// with the COALESCED pattern W[c*64+cc] (64 consecutive floats per wave per
// c — one 256B segment per load instruction; R11 proved per-thread-row
// streaming trades 4x fewer instrs for ~16x more cache-line transactions
// and regresses). c-ascending FMA chain -> bit-identical.
// y==2 / y==4 (AWG K slabs) are stored PACKED f16 (uint2 per 4 dims).
// ---------------------------------------------------------------------------
__global__ __launch_bounds__(256) void kvq_proj_kernel(
    const float* __restrict__ enc, const float* __restrict__ q,
    const float* __restrict__ calWq,
    const float* __restrict__ calWk, const float* __restrict__ calWv,
    const float* __restrict__ mWk, const float* __restrict__ mWv,
    float* __restrict__ kv, float* __restrict__ qp)
{
  const int y = blockIdx.y;
  if (y < 6 && blockIdx.x >= 188) return;
  __shared__ __align__(16) float xs[16][64];
  const int t = threadIdx.x, rr = t >> 6, cc = t & 63;
  const float* W;
  const float* src;
  float* dst;
  float scale = 1.f;
  int nrows = 3000;
  switch (y) {
    case 0: W = calWk; src = enc; dst = kv;               break;
    case 1: W = calWv; src = enc; dst = kv + 192000;      break;
    case 2: W = mWk;        src = enc; dst = kv + 384000; break;
    case 3: W = mWv;        src = enc; dst = kv + 576000; break;
    case 4: W = mWk + 4096; src = enc; dst = kv + 768000; break;
    case 5: W = mWv + 4096; src = enc; dst = kv + 960000; break;
    default: W = calWq; src = q; dst = qp; scale = 0.25f; nrows = 12000; break;
  }
  const bool packK = (y == 2) || (y == 4);
  const int base = blockIdx.x * 16;
  {
    const int grow = base + (t >> 4);
    float4 v = {0.f, 0.f, 0.f, 0.f};
    if (grow < nrows) v = *(const float4*)&src[(size_t)grow * 64 + (t & 15) * 4];
    ((float4*)xs)[t] = v;
  }
  __syncthreads();
  float acc[4] = {0.f, 0.f, 0.f, 0.f};
  #pragma unroll 8
  for (int c = 0; c < 64; ++c) {
    const float w = W[c * 64 + cc];
    #pragma unroll
    for (int p = 0; p < 4; ++p) acc[p] = fmaf(xs[p * 4 + rr][c], w, acc[p]);
  }
  #pragma unroll
  for (int p = 0; p < 4; ++p) {
    const int grow = base + p * 4 + rr;
    if (packK) {
      const float accN = __shfl_xor(acc[p], 1);   // partner dim (cc^1)
      if (!(cc & 1) && grow < nrows)
        ((unsigned int*)dst)[(size_t)grow * 32 + (cc >> 1)] = packh2(acc[p], accN);
    } else if (grow < nrows) {
      dst[(size_t)grow * 64 + cc] = acc[p] * scale;
    }
  }
}

// ---------------------------------------------------------------------------
// CROSS attention via MFMA (flash-lite, no max subtraction — logits bounded).
// grid (47, NH, B), block 256 (4 waves); wave owns 16 q-rows (block: 64).
// ---------------------------------------------------------------------------
__global__ __launch_bounds__(256) void cross_attn_kernel(
    const float* __restrict__ qp, const float* __restrict__ kp,
    const float* __restrict__ vp, float* __restrict__ ao)
{
  extern __shared__ char smem[];
  unsigned short* Kl = (unsigned short*)smem;       // [750][18]
  unsigned short* Vt = Kl + 750 * 18;               // [16][754]
  unsigned short* Pt = Vt + 16 * 754;               // [4 waves][16][18]

  const int t = threadIdx.x;
  const int h = blockIdx.y, b = blockIdx.z;
  const float* kslab = kp + (size_t)(b * LK) * 64 + h * 16;
  const float* vslab = vp + (size_t)(b * LK) * 64 + h * 16;

  // stage K (row-major f16, pitch 18) and V transposed ([d][key])
  for (int k = t; k < LK; k += 256) {
    const float4* ks = (const float4*)(kslab + (size_t)k * 64);
    const float4* vs = (const float4*)(vslab + (size_t)k * 64);
    unsigned int* kr = (unsigned int*)(Kl + k * 18);
    #pragma unroll
    for (int q4 = 0; q4 < 4; ++q4) {
      float4 a = ks[q4], v = vs[q4];
      kr[q4 * 2]     = packh2(a.x, a.y);
      kr[q4 * 2 + 1] = packh2(a.z, a.w);
      Vt[(q4 * 4 + 0) * 754 + k] = f2h(v.x);
      Vt[(q4 * 4 + 1) * 754 + k] = f2h(v.y);
      Vt[(q4 * 4 + 2) * 754 + k] = f2h(v.z);
      Vt[(q4 * 4 + 3) * 754 + k] = f2h(v.w);
    }
  }
  // zero V pad keys 750..751 (P is masked there, but 0*NaN would poison O)
  if (t < 32) Vt[(t & 15) * 754 + 750 + (t >> 4)] = 0;
  __syncthreads();

  const int wave = t >> 6, lane = t & 63;
  const int col = lane & 15, quad = lane >> 4;
  const int qbase = blockIdx.x * 64 + wave * 16;
  unsigned short* Pt_w = Pt + wave * 288;   // [16][18]

  // Q A-fragment: A[m=col][k=quad*4+j], constant across tiles
  int qrow = qbase + col; if (qrow >= LQ) qrow = LQ - 1;
  const float* qptr = qp + ((size_t)(b * LQ + qrow)) * 64 + h * 16 + quad * 4;
  half4_t aQ;
  {
    unsigned long long v = ((unsigned long long)packh2(qptr[2], qptr[3]) << 32)
                         | packh2(qptr[0], qptr[1]);
    __builtin_memcpy(&aQ, &v, 8);
  }

  f32x4 O = {0.f, 0.f, 0.f, 0.f};
  float Zp[4] = {0.f, 0.f, 0.f, 0.f};
  const f32x4 zeroC = {0.f, 0.f, 0.f, 0.f};

  for (int tile = 0; tile < 47; ++tile) {
    const int key = tile * 16 + col;
    // B-fragment K^T: B[k=quad*4+j][n=col] = K[key=n][k]
    const half4_t bK = h4_from(Kl + key * 18 + quad * 4);
    f32x4 S = MFMA16(aQ, bK, zeroC);
    // exp + mask (C layout: col=lane&15 -> key, row=quad*4+r)
    const bool valid = key < LK;
    float e0 = valid ? __expf(S[0]) : 0.f;
    float e1 = valid ? __expf(S[1]) : 0.f;
    float e2 = valid ? __expf(S[2]) : 0.f;
    float e3 = valid ? __expf(S[3]) : 0.f;
    Zp[0] += e0; Zp[1] += e1; Zp[2] += e2; Zp[3] += e3;
    // C->A transpose through wave-private LDS tile (barrier-free)
    Pt_w[(quad * 4 + 0) * 18 + col] = f2h(e0);
    Pt_w[(quad * 4 + 1) * 18 + col] = f2h(e1);
    Pt_w[(quad * 4 + 2) * 18 + col] = f2h(e2);
    Pt_w[(quad * 4 + 3) * 18 + col] = f2h(e3);
    const half4_t aP = h4_from(Pt_w + col * 18 + quad * 4);
    // B-fragment V: B[k=quad*4+j][n=col] = V[key=tile*16+quad*4+j][d=col]
    const half4_t bV = h4_from(Vt + col * 754 + tile * 16 + quad * 4);
    O = MFMA16(aP, bV, O);
  }

  // reduce Z across the 16-lane col group (rows quad*4+r live there)
  #pragma unroll
  for (int r = 0; r < 4; ++r) {
    float z = Zp[r];
    z += __shfl_xor(z, 1);
    z += __shfl_xor(z, 2);
    z += __shfl_xor(z, 4);
    z += __shfl_xor(z, 8);
    Zp[r] = z;
  }

  #pragma unroll
  for (int r = 0; r < 4; ++r) {
    const int orow = qbase + quad * 4 + r;
    if (orow < LQ)
      ao[((size_t)(b * LQ + orow)) * 64 + h * 16 + col] = O[r] / Zp[r];
  }
}

// ---------------------------------------------------------------------------
// AWG attention v5 (R8 verbatim — the proven 59.3 µs variant).
// grid (94, NH, B), block 512 (8 waves, 4 q-rows/wave). 4 blocks/CU.
// ---------------------------------------------------------------------------
__global__ __launch_bounds__(512) void awg_attn_kernel(
    const float* __restrict__ qp, const unsigned int* __restrict__ kp,
    const float* __restrict__ vp, float* __restrict__ ao)
{
  extern __shared__ char smem[];
  uint2*          KT2   = (uint2*)smem;                                      // [4][PITCH] = 24,032 B
  unsigned int*   candV = (unsigned int*)(smem + 4 * PITCH * 8);             // [8][4][64] = 8,192
  unsigned short* candK = (unsigned short*)(smem + 4 * PITCH * 8 + 8192);    // [8][4][64] = 4,096
  float*          selW  = (float*)(smem + 4 * PITCH * 8 + 8192 + 4096);      // [8][4][24] = 3,072
  unsigned short* selK  = (unsigned short*)(smem + 4 * PITCH * 8 + 8192 + 4096 + 3072); // 1,536

  const int t = threadIdx.x;
  const int h = blockIdx.y, b = blockIdx.z;
  const unsigned int* kslab = kp + ((size_t)(b * LK)) * 32 + h * 8;

  for (int k = t; k < LK; k += 512) {
    const uint2* ks = (const uint2*)(kslab + (size_t)k * 32);
    #pragma unroll
    for (int d4 = 0; d4 < 4; ++d4) KT2[d4 * PITCH + k] = ks[d4];
  }
  __syncthreads();

  const int wave = t >> 6, lane = t & 63;
  const unsigned long long below = (1ull << lane) - 1ull;
  unsigned int*   cV = candV + wave * 256;
  unsigned short* cK = candK + wave * 256;
  float*          sW = selW + wave * 96;
  unsigned short* sK = selK + wave * 96;

  // pad select arrays (wave-private; unwritten tail -> exp()==0 in gather)
  sW[lane] = -3.0e38f; sK[lane] = 0;
  if (lane < 32) { sW[64 + lane] = -3.0e38f; sK[64 + lane] = 0; }
  // zero candidate values (pads sort to the tail and never pass >= T)
  #pragma unroll
  for (int r = 0; r < 4; ++r) cV[r * 64 + lane] = 0u;

  const int r0 = blockIdx.x * 32 + wave * 4;
  int r0r = r0; if (r0r > LQ - 4) r0r = LQ - 4;   // clamp reads; stores guarded
  const float* qrow = qp + ((size_t)(b * LQ + r0r)) * 64 + h * 16;
  unsigned int qw[4][8];   // wave-uniform packed f16 q -> SGPRs
  #pragma unroll
  for (int r = 0; r < 4; ++r) {
    #pragma unroll
    for (int i = 0; i < 8; ++i)
      qw[r][i] = bcastu(packh2(qrow[r * 64 + 2 * i], qrow[r * 64 + 2 * i + 1]));
  }

  float lg[4][12];
  #pragma unroll
  for (int tt = 0; tt < 12; ++tt) {
    const int k = lane + (tt << 6);
    if (tt < 11 || k < LK) {
      float a0 = 0.f, a1 = 0.f, a2 = 0.f, a3 = 0.f;
      #pragma unroll
      for (int d4 = 0; d4 < 4; ++d4) {
        const uint2 w = KT2[d4 * PITCH + k];
        a0 = dot2(w.x, u2h(qw[0][2 * d4]), a0); a0 = dot2(w.y, u2h(qw[0][2 * d4 + 1]), a0);
        a1 = dot2(w.x, u2h(qw[1][2 * d4]), a1); a1 = dot2(w.y, u2h(qw[1][2 * d4 + 1]), a1);
        a2 = dot2(w.x, u2h(qw[2][2 * d4]), a2); a2 = dot2(w.y, u2h(qw[2][2 * d4 + 1]), a2);
        a3 = dot2(w.x, u2h(qw[3][2 * d4]), a3); a3 = dot2(w.y, u2h(qw[3][2 * d4 + 1]), a3);
      }
      lg[0][tt] = a0; lg[1][tt] = a1; lg[2][tt] = a2; lg[3][tt] = a3;
    } else {
      lg[0][tt] = -3.0e38f; lg[1][tt] = -3.0e38f;
      lg[2][tt] = -3.0e38f; lg[3][tt] = -3.0e38f;
    }
  }

  // per-lane heads (max of this lane's 12 keys) per row
  unsigned int hs[4];
  #pragma unroll
  for (int r = 0; r < 4; ++r) {
    float m = lg[r][0];
    #pragma unroll
    for (int tt = 1; tt < 12; ++tt) m = fmaxf(m, lg[r][tt]);
    hs[r] = f2sort(m);
  }

  // stage 1: sort heads descending -> L = exact 16th largest head
  sort64u_desc4(hs);
  unsigned int L[4];
  #pragma unroll
  for (int r = 0; r < 4; ++r) L[r] = __shfl(hs[r], 15);

  // stage 2: compact candidates (value u32 + key u16)
  int cb[4] = {0, 0, 0, 0};
  #pragma unroll
  for (int tt = 0; tt < 12; ++tt) {
    const int k = lane + (tt << 6);
    #pragma unroll
    for (int r = 0; r < 4; ++r) {
      const unsigned int s = f2sort(lg[r][tt]);
      const bool p = s >= L[r];
      const unsigned long long m = __ballot(p);
      if (p) {
        const int pos = cb[r] + (int)__popcll(m & below);
        if (pos < 64) { cV[r * 64 + pos] = s; cK[r * 64 + pos] = (unsigned short)k; }
      }
      cb[r] += (int)__popcll(m);
    }
  }

  // stage 3: sort candidate VALUES descending -> T@lane15, M@lane0
  unsigned int su[4], so[4];
  #pragma unroll
  for (int r = 0; r < 4; ++r) { su[r] = cV[r * 64 + lane]; so[r] = su[r]; }
  sort64u_desc4(so);
  unsigned int T[4]; float Mv[4];
  #pragma unroll
  for (int r = 0; r < 4; ++r) {
    T[r]  = __shfl(so[r], 15);
    Mv[r] = sort2f(__shfl(so[r], 0));
  }

  // kept set (value >= T; pads su==0 < T always); compact write, cap 24
  #pragma unroll
  for (int r = 0; r < 4; ++r) {
    const bool w = su[r] >= T[r];
    const unsigned long long mw = __ballot(w);
    if (w) {
      const int pos = (int)__popcll(mw & below);
      if (pos < 24) { sW[r * 24 + pos] = sort2f(su[r]); sK[r * 24 + pos] = cK[r * 64 + lane]; }
    }
  }

  // gather: 16 lanes per row (dd = dim), fixed 24 slots, fully unrolled
  const int dd = lane & 15;
  const int rsel = lane >> 4;
  const float ref = (rsel == 0) ? Mv[0] : (rsel == 1) ? Mv[1] : (rsel == 2) ? Mv[2] : Mv[3];
  const float* cwr = sW + rsel * 24;
  const unsigned short* cir = sK + rsel * 24;
  const float* vbase = vp + (size_t)(b * LK) * 64 + h * 16 + dd;
  float acc = 0.f, Z = 0.f;
  #pragma unroll
  for (int j = 0; j < 24; ++j) {
    const float e = __expf(cwr[j] - ref);
    Z += e;
    acc = fmaf(e, vbase[(size_t)cir[j] * 64], acc);
  }
  if (r0 + rsel < LQ)
    ao[((size_t)(b * LQ + r0 + rsel)) * 64 + h * 16 + dd] = acc / Z;
}

// ---------------------------------------------------------------------------
// FUSED cross-FFN + MGAN pre (layer 0). 16 rows/block, grid 750, 4
// rows/thread (R8 verbatim — coalesced weight reads W[c*64+cc]).
// ---------------------------------------------------------------------------
__global__ __launch_bounds__(256) void ffn_pre_kernel(
    const float* __restrict__ ao, const float* __restrict__ qres,
    const float* __restrict__ Wo,
    const float* __restrict__ g1, const float* __restrict__ b1n,
    const float* __restrict__ W1, const float* __restrict__ bb1,
    const float* __restrict__ W2, const float* __restrict__ bb2,
    const float* __restrict__ g2, const float* __restrict__ b2n,
    const float* __restrict__ lng, const float* __restrict__ lnb,
    const float* __restrict__ fc1W, const float* __restrict__ fc1b,
    const float* __restrict__ fc2W, const float* __restrict__ fc2b,
    const float* __restrict__ Wq,
    float* __restrict__ qn, float* __restrict__ sg, float* __restrict__ qp)
{
  __shared__ float xs[16][64];
  __shared__ float hsm[16][256];
  const int t = threadIdx.x, rr = t >> 6, cc = t & 63;
  const size_t base = (size_t)blockIdx.x * 16;
  for (int i = t; i < 1024; i += 256) xs[i >> 6][i & 63] = ao[base * 64 + i];
  __syncthreads();
  float acc[4];
  #pragma unroll
  for (int p = 0; p < 4; ++p) acc[p] = 0.f;
  #pragma unroll 8
  for (int c = 0; c < 64; ++c) {
    const float w = Wo[c * 64 + cc];
    #pragma unroll
    for (int p = 0; p < 4; ++p) acc[p] = fmaf(xs[p * 4 + rr][c], w, acc[p]);
  }
  #pragma unroll
  for (int p = 0; p < 4; ++p) acc[p] += qres[(base + p * 4 + rr) * 64 + cc];
  __syncthreads();
  float x1[4];
  #pragma unroll
  for (int p = 0; p < 4; ++p) {
    x1[p] = row_ln(acc[p], g1[cc], b1n[cc]);
    xs[p * 4 + rr][cc] = x1[p];
  }
  __syncthreads();
  {
    float hv[16];
    #pragma unroll
    for (int r = 0; r < 16; ++r) hv[r] = 0.f;
    #pragma unroll 4
    for (int c = 0; c < 64; ++c) {
      const float w = W1[c * 256 + t];
      #pragma unroll
      for (int r = 0; r < 16; ++r) hv[r] = fmaf(xs[r][c], w, hv[r]);
    }
    const float bb = bb1[t];
    #pragma unroll
    for (int r = 0; r < 16; ++r) hsm[r][t] = fmaxf(hv[r] + bb, 0.f);
  }
  __syncthreads();
  float acc2[4];
  #pragma unroll
  for (int p = 0; p < 4; ++p) acc2[p] = bb2[cc];
  #pragma unroll 8
  for (int c = 0; c < 256; ++c) {
    const float w = W2[c * 64 + cc];
    #pragma unroll
    for (int p = 0; p < 4; ++p) acc2[p] = fmaf(hsm[p * 4 + rr][c], w, acc2[p]);
  }
  // x = LN(ffn + x1); qn = LN(x) — xs reuse is safe: last xs read was
  // guarded by the post-W1 barrier above.
  float qv[4];
  #pragma unroll
  for (int p = 0; p < 4; ++p) {
    const float xv = row_ln(acc2[p] + x1[p], g2[cc], b2n[cc]);
    qv[p] = row_ln(xv, lng[cc], lnb[cc]);
    qn[(base + p * 4 + rr) * 64 + cc] = qv[p];
  }
  __syncthreads();
  #pragma unroll
  for (int p = 0; p < 4; ++p) xs[p * 4 + rr][cc] = qv[p];
  __syncthreads();
  float d1[4], d2[4];
  #pragma unroll
  for (int p = 0; p < 4; ++p) { d1[p] = fc1b[cc]; d2[p] = fc2b[cc]; }
  #pragma unroll 4
  for (int c = 0; c < 64; ++c) {
    const float w1 = fc1W[c * 64 + cc];
    const float w2 = fc2W[c * 64 + cc];
    #pragma unroll
    for (int p = 0; p < 4; ++p) {
      const float xq = xs[p * 4 + rr][c];
      d1[p] = fmaf(xq, w1, d1[p]);
      d2[p] = fmaf(xq, w2, d2[p]);
    }
  }
  float sv[4];
  #pragma unroll
  for (int p = 0; p < 4; ++p) {
    sv[p] = sigmoidf(d1[p]) * d2[p];
    sg[(base + p * 4 + rr) * 64 + cc] = sv[p];
  }
  __syncthreads();
  #pragma unroll
  for (int p = 0; p < 4; ++p) xs[p * 4 + rr][cc] = sv[p];
  __syncthreads();
  float aq[4];
  #pragma unroll
  for (int p = 0; p < 4; ++p) aq[p] = 0.f;
  #pragma unroll 8
  for (int c = 0; c < 64; ++c) {
    const float w = Wq[c * 64 + cc];
    #pragma unroll
    for (int p = 0; p < 4; ++p) aq[p] = fmaf(xs[p * 4 + rr][c], w, aq[p]);
  }
  #pragma unroll
  for (int p = 0; p < 4; ++p)
    qp[(base + p * 4 + rr) * 64 + cc] = aq[p] * 0.25f;
}

// ---------------------------------------------------------------------------
// Fused awg_out(layer i) + mgan_pre(layer i+1): x never touches HBM.
// 16 rows/block, grid 750, 4 rows/thread (R8 verbatim).
// ---------------------------------------------------------------------------
__global__ __launch_bounds__(256) void out_pre_kernel(
    const float* __restrict__ ao, const float* __restrict__ sg,
    const float* __restrict__ qn, const float* __restrict__ Wo,
    const float* __restrict__ g_, const float* __restrict__ b_,
    const float* __restrict__ lng, const float* __restrict__ lnb,
    const float* __restrict__ W1, const float* __restrict__ bb1,
    const float* __restrict__ W2, const float* __restrict__ bb2,
    const float* __restrict__ Wq,
    float* __restrict__ qn_out, float* __restrict__ sg_out,
    float* __restrict__ qp_out)
{
  __shared__ float xs[16][64];
  const int t = threadIdx.x, rr = t >> 6, cc = t & 63;
  const size_t base = (size_t)blockIdx.x * 16;
  for (int i = t; i < 1024; i += 256) xs[i >> 6][i & 63] = ao[base * 64 + i];
  __syncthreads();
  float accp[4], sgv[4];
  #pragma unroll
  for (int p = 0; p < 4; ++p) accp[p] = 0.f;
  #pragma unroll 8
  for (int c = 0; c < 64; ++c) {
    const float w = Wo[c * 64 + cc];
    #pragma unroll
    for (int p = 0; p < 4; ++p) accp[p] = fmaf(xs[p * 4 + rr][c], w, accp[p]);
  }
  #pragma unroll
  for (int p = 0; p < 4; ++p) {
    sgv[p] = sg[(base + p * 4 + rr) * 64 + cc];
    accp[p] += sgv[p];
  }
  __syncthreads();
  float qv[4];
  #pragma unroll
  for (int p = 0; p < 4; ++p) {
    const size_t idx = (base + p * 4 + rr) * 64 + cc;
    const float awg = row_ln(accp[p], g_[cc], b_[cc]);
    const float xv = qn[idx] + sgv[p] * sigmoidf(awg);
    qv[p] = row_ln(xv, lng[cc], lnb[cc]);
    qn_out[idx] = qv[p];
    xs[p * 4 + rr][cc] = qv[p];
  }
  __syncthreads();
  float d1[4], d2[4];
  #pragma unroll
  for (int p = 0; p < 4; ++p) { d1[p] = bb1[cc]; d2[p] = bb2[cc]; }
  #pragma unroll 4
  for (int c = 0; c < 64; ++c) {
    const float w1 = W1[c * 64 + cc];
    const float w2 = W2[c * 64 + cc];
    #pragma unroll
    for (int p = 0; p < 4; ++p) {
      const float xv = xs[p * 4 + rr][c];
      d1[p] = fmaf(xv, w1, d1[p]);
      d2[p] = fmaf(xv, w2, d2[p]);
    }
  }
  __syncthreads();
  float sv[4];
  #pragma unroll
  for (int p = 0; p < 4; ++p) {
    sv[p] = sigmoidf(d1[p]) * d2[p];
    sg_out[(base + p * 4 + rr) * 64 + cc] = sv[p];
    xs[p * 4 + rr][cc] = sv[p];
  }
  __syncthreads();
  float aq[4];
  #pragma unroll
  for (int p = 0; p < 4; ++p) aq[p] = 0.f;
  #pragma unroll 8
  for (int c = 0; c < 64; ++c) {
    const float w = Wq[c * 64 + cc];
    #pragma unroll
    for (int p = 0; p < 4; ++p) aq[p] = fmaf(xs[p * 4 + rr][c], w, aq[p]);
  }
  #pragma unroll
  for (int p = 0; p < 4; ++p)
    qp_out[(base + p * 4 + rr) * 64 + cc] = aq[p] * 0.25f;
}

// ---------------------------------------------------------------------------
// Fused awg_out(layer 1) + head: out = sigmoid(x2 @ fcW + fcb).
// 16 rows/block, grid 750, 4 rows/thread (R8 verbatim).
// ---------------------------------------------------------------------------
__global__ __launch_bounds__(256) void out_final_kernel(
    const float* __restrict__ ao, const float* __restrict__ sg,
    const float* __restrict__ qn, const float* __restrict__ Wo,
    const float* __restrict__ g_, const float* __restrict__ b_,
    const float* __restrict__ fw, const float* __restrict__ fb,
    float* __restrict__ out)
{
  __shared__ float xs[16][64];
  const int t = threadIdx.x, rr = t >> 6, cc = t & 63;
  const size_t base = (size_t)blockIdx.x * 16;
  for (int i = t; i < 1024; i += 256) xs[i >> 6][i & 63] = ao[base * 64 + i];
  __syncthreads();
  float accp[4];
  #pragma unroll
  for (int p = 0; p < 4; ++p) accp[p] = 0.f;
  #pragma unroll 8
  for (int c = 0; c < 64; ++c) {
    const float w = Wo[c * 64 + cc];
    #pragma unroll
    for (int p = 0; p < 4; ++p) accp[p] = fmaf(xs[p * 4 + rr][c], w, accp[p]);
  }
  #pragma unroll
  for (int p = 0; p < 4; ++p) {
    const size_t idx = (base + p * 4 + rr) * 64 + cc;
    const float sgv = sg[idx];
    const float a = accp[p] + sgv;
    const float awg = row_ln(a, g_[cc], b_[cc]);
    const float xv = qn[idx] + sgv * sigmoidf(awg);
    float v = xv * fw[cc];
    #pragma unroll
    for (int off = 32; off > 0; off >>= 1) v += __shfl_xor(v, off);
    if (cc == 0) out[base + p * 4 + rr] = sigmoidf(v + fb[0]);
  }
}

// ---------------------------------------------------------------------------
extern "C" void kernel_launch(void* const* d_in, const int* in_sizes, int n_in,
                              void* d_out, int out_size, void* d_ws, size_t ws_size,
                              hipStream_t stream) {
  (void)in_sizes; (void)n_in; (void)out_size; (void)ws_size;

  const float* q     = (const float*)d_in[0];
  const float* enc   = (const float*)d_in[1];
  const float* calWq = (const float*)d_in[2];
  const float* calWk = (const float*)d_in[3];
  const float* calWv = (const float*)d_in[4];
  const float* calWo = (const float*)d_in[5];
  const float* ln1g  = (const float*)d_in[6];
  const float* ln1b  = (const float*)d_in[7];
  const float* W1    = (const float*)d_in[8];
  const float* b1v   = (const float*)d_in[9];
  const float* W2    = (const float*)d_in[10];
  const float* b2v   = (const float*)d_in[11];
  const float* ln2g  = (const float*)d_in[12];
  const float* ln2b  = (const float*)d_in[13];
  const float* mlng  = (const float*)d_in[14];
  const float* mlnb  = (const float*)d_in[15];
  const float* mfc1W = (const float*)d_in[16];
  const float* mfc1b = (const float*)d_in[17];
  const float* mfc2W = (const float*)d_in[18];
  const float* mfc2b = (const float*)d_in[19];
  const float* mWq   = (const float*)d_in[20];
  const float* mWk   = (const float*)d_in[21];
  const float* mWv   = (const float*)d_in[22];
  const float* mWo   = (const float*)d_in[23];
  const float* malng = (const float*)d_in[24];
  const float* malnb = (const float*)d_in[25];
  const float* fcW   = (const float*)d_in[26];
  const float* fcb   = (const float*)d_in[27];
  float* out = (float*)d_out;

  float* ws  = (float*)d_ws;
  float* kv  = ws + WS_KV;
  float* qp  = ws + WS_QP;
  float* aob = ws + WS_AO;
  float* qnb = ws + WS_QN;
  float* sgb = ws + WS_SG;

  const size_t crossLds = (750 * 18 + 16 * 754 + 4 * 288) * 2;        // 53,432 B
  const size_t awgLds   = 4 * PITCH * 8 + 8192 + 4096 + 3072 + 1536;  // 40,928 B

  // 1) all K/V projections + cross q-projection in one dispatch
  //    (awg K slabs y==2/y==4 stored packed f16)
  kvq_proj_kernel<<<dim3(750, 7), 256, 0, stream>>>(enc, q, calWq, calWk, calWv,
                                                    mWk, mWv, kv, qp);

  // 2) cross attention (MFMA flash-lite) + fused FFN+MGAN-pre epilogue
  cross_attn_kernel<<<dim3(47, NH_, B_), 256, crossLds, stream>>>(qp, kv, kv + 192000, aob);
  ffn_pre_kernel<<<750, 256, 0, stream>>>(aob, q, calWo, ln1g, ln1b,
                                          W1, b1v, W2, b2v, ln2g, ln2b,
                                          mlng, mlnb, mfc1W, mfc1b,
                                          mfc2W, mfc2b, mWq, qnb, sgb, qp);

  // 3) MGAN layer 0 attention + fused out/pre
  awg_attn_kernel<<<dim3(94, NH_, B_), 512, awgLds, stream>>>(
      qp, (const unsigned int*)(kv + 2 * 192000), kv + 3 * 192000, aob);
  out_pre_kernel<<<750, 256, 0, stream>>>(aob, sgb, qnb, mWo, malng, malnb,
                                          mlng + 64, mlnb + 64,
                                          mfc1W + 4096, mfc1b + 64,
                                          mfc2W + 4096, mfc2b + 64,
                                          mWq + 4096, qnb, sgb, qp);

  // 4) MGAN layer 1 + head
  awg_attn_kernel<<<dim3(94, NH_, B_), 512, awgLds, stream>>>(
      qp, (const unsigned int*)(kv + 4 * 192000), kv + 5 * 192000, aob);
  out_final_kernel<<<750, 256, 0, stream>>>(aob, sgb, qnb, mWo + 4096,
                                            malng + 64, malnb + 64, fcW, fcb, out);
}